// Round 10
// baseline (224.902 us; speedup 1.0000x reference)
//
#include <hip/hip_runtime.h>
#include <math.h>

#define N_NODES 40000
#define N_EDGES 640000
#define D 128
#define H 8
#define C 16
#define NB_SCAN 157  // ceil(40000/256)
#define NBG 625      // 40000/64 exactly
#define KP 136       // sA k-stride (bf16 elems)

typedef __attribute__((ext_vector_type(8))) short short8;   // 8 bf16 (4 VGPRs)
typedef __attribute__((ext_vector_type(4))) float floatx4;  // MFMA C/D

// ws layout (float offsets):
//  xh   : 0          .. 2,560,000   (N*128 bf16 stored as ushort)
//  al   : 5,120,000  .. 5,440,000   (N*8)
//  ar   : 5,440,000  .. 5,760,000   (N*8)
//  pexp : 5,760,000  .. 10,880,000  (E*8 fp32, dst-sorted exp(logit))
//  psrc : 10,880,000 .. 11,520,000  (E ints, dst-sorted src ids)
//  rowL : 11,520,000 .. 11,560,000  (N ints, LOCAL exclusive prefix)
//  cnt  : 11,700,000 .. 11,740,000  (N ints)   | zeroed together
//  cur  : 11,740,000 .. 11,780,000  (N ints)   | (one memset)
//  bsum : 11,800,000 .. +157
//  bpre : 11,810,000 .. +157
//  wt   : 11,900,000 .. +8,192 floats (2x 128x128 bf16 transposed weights)
//  einv : 12,000,000 .. 12,640,000  (E ints, p -> e permutation)

__device__ __forceinline__ unsigned short f2bf(float f) {
  const unsigned u = __float_as_uint(f);
  return (unsigned short)((u + 0x7FFFu + ((u >> 16) & 1u)) >> 16);  // RNE
}
__device__ __forceinline__ float bflo(unsigned p) {
  return __uint_as_float(p << 16);
}
__device__ __forceinline__ float bfhi(unsigned p) {
  return __uint_as_float(p & 0xFFFF0000u);
}

// Pre-transpose W (fp32 [k][n]) -> wt (bf16 [g][n][k]). 64 KB total.
__global__ void k_prep(const float* __restrict__ Wlin,
                       const float* __restrict__ Wres,
                       unsigned short* __restrict__ wt)
{
  const int n = blockIdx.x, k = threadIdx.x, g = blockIdx.y;
  const float* W = g ? Wres : Wlin;
  wt[((g * 128 + n) * 128) + k] = f2bf(W[(long)k * 128 + n]);
}

// MFMA bf16 GEMM, 64-row blocks. blockIdx.y: 0 = xh=bf16(feat@Wlin);
// 1 = outp=feat@Wres; 2 = dst-histogram. B frags from global wt (no sB).
// One LDS buffer: sA bf16 staging, reused post-MFMA as sD f32 for
// coalesced full-line stores.
__global__ __launch_bounds__(256, 4) void k_gemm(
    const float* __restrict__ feat, const unsigned short* __restrict__ wt,
    unsigned short* __restrict__ xh, float* __restrict__ outp,
    const int* __restrict__ dst, int* __restrict__ cnt)
{
  __shared__ float smemf[64 * 132];   // 33,792 B
  const int t = threadIdx.x;

  if (blockIdx.y == 2) {              // fused histogram
    const int stride = NBG * 256;
    for (int e = blockIdx.x * 256 + t; e < N_EDGES; e += stride)
      atomicAdd(&cnt[dst[e]], 1);
    return;
  }

  short* sA = (short*)smemf;          // [64][KP]
  float* sD = smemf;                  // [64][132]
  const int row0 = blockIdx.x * 64;
  const int g = blockIdx.y;

  {
    const int kq = t & 31;
    const int rb = (t >> 5) * 8;
    #pragma unroll
    for (int i = 0; i < 8; ++i) {
      const int r = rb + i;
      const float4 f = *(const float4*)&feat[(long)(row0 + r) * 128 + kq * 4];
      const unsigned lo = (unsigned)f2bf(f.x) | ((unsigned)f2bf(f.y) << 16);
      const unsigned hi = (unsigned)f2bf(f.z) | ((unsigned)f2bf(f.w) << 16);
      *(uint2*)&sA[r * KP + kq * 4] = make_uint2(lo, hi);
    }
  }

  const int w = t >> 6, lane = t & 63;
  const int c15 = lane & 15, q = lane >> 4;

  short8 bfr[4][2];
  const unsigned short* Wt = wt + g * 16384;
  #pragma unroll
  for (int kc = 0; kc < 4; ++kc)
    #pragma unroll
    for (int nt = 0; nt < 2; ++nt) {
      const int n = (w * 2 + nt) * 16 + c15;
      bfr[kc][nt] = *(const short8*)&Wt[n * 128 + kc * 32 + q * 8];
    }
  __syncthreads();

  floatx4 acc[4][2];
  #pragma unroll
  for (int mt = 0; mt < 4; ++mt) {
    acc[mt][0] = (floatx4){0.f, 0.f, 0.f, 0.f};
    acc[mt][1] = (floatx4){0.f, 0.f, 0.f, 0.f};
  }
  #pragma unroll
  for (int kc = 0; kc < 4; ++kc)
    #pragma unroll
    for (int mt = 0; mt < 4; ++mt) {
      const short8 afr = *(const short8*)&sA[(mt * 16 + c15) * KP + kc * 32 + q * 8];
      acc[mt][0] = __builtin_amdgcn_mfma_f32_16x16x32_bf16(afr, bfr[kc][0], acc[mt][0], 0, 0, 0);
      acc[mt][1] = __builtin_amdgcn_mfma_f32_16x16x32_bf16(afr, bfr[kc][1], acc[mt][1], 0, 0, 0);
    }
  __syncthreads();

  #pragma unroll
  for (int mt = 0; mt < 4; ++mt)
    #pragma unroll
    for (int nt = 0; nt < 2; ++nt) {
      const int col = (w * 2 + nt) * 16 + c15;
      #pragma unroll
      for (int r = 0; r < 4; ++r)
        sD[(mt * 16 + q * 4 + r) * 132 + col] = acc[mt][nt][r];
    }
  __syncthreads();

  const int orow = t >> 2, qt = t & 3;
  const int grow = row0 + orow;
  if (g == 0) {
    #pragma unroll
    for (int i = 0; i < 4; ++i) {
      const float4 v0 = *(const float4*)&sD[orow * 132 + qt * 32 + i * 8];
      const float4 v1 = *(const float4*)&sD[orow * 132 + qt * 32 + i * 8 + 4];
      uint4 u;
      u.x = (unsigned)f2bf(v0.x) | ((unsigned)f2bf(v0.y) << 16);
      u.y = (unsigned)f2bf(v0.z) | ((unsigned)f2bf(v0.w) << 16);
      u.z = (unsigned)f2bf(v1.x) | ((unsigned)f2bf(v1.y) << 16);
      u.w = (unsigned)f2bf(v1.z) | ((unsigned)f2bf(v1.w) << 16);
      *(uint4*)&xh[(long)grow * 128 + qt * 32 + i * 8] = u;
    }
  } else {
    #pragma unroll
    for (int i = 0; i < 8; ++i) {
      const float4 v = *(const float4*)&sD[orow * 132 + qt * 32 + i * 4];
      *(float4*)&outp[(long)grow * 128 + qt * 32 + i * 4] = v;
    }
  }
}

// alpha_l/r from xh (bf16): thread = (node, head), 32B coalesced reads.
__global__ __launch_bounds__(256) void k_alpha(
    const unsigned short* __restrict__ xh, const float* __restrict__ attl,
    const float* __restrict__ attr, float* __restrict__ al, float* __restrict__ ar)
{
  const int gid = blockIdx.x * 256 + threadIdx.x;
  if (gid >= N_NODES * 8) return;
  const int n = gid >> 3, h = gid & 7;
  const uint4 u0 = *(const uint4*)&xh[(long)n * 128 + h * 16];
  const uint4 u1 = *(const uint4*)&xh[(long)n * 128 + h * 16 + 8];
  const unsigned vs[8] = {u0.x, u0.y, u0.z, u0.w, u1.x, u1.y, u1.z, u1.w};
  float sl = 0.f, sr = 0.f;
  #pragma unroll
  for (int j = 0; j < 8; ++j) {
    const float xlo = bflo(vs[j]), xhi = bfhi(vs[j]);
    sl = fmaf(xlo, attl[h * 16 + 2 * j], fmaf(xhi, attl[h * 16 + 2 * j + 1], sl));
    sr = fmaf(xlo, attr[h * 16 + 2 * j], fmaf(xhi, attr[h * 16 + 2 * j + 1], sr));
  }
  al[gid] = sl;
  ar[gid] = sr;
}

__global__ __launch_bounds__(256) void k_scan_local(
    const int* __restrict__ cnt, int* __restrict__ rowL, int* __restrict__ bsum)
{
  __shared__ int sd[256];
  const int t = threadIdx.x;
  const int i = blockIdx.x * 256 + t;
  const int v = (i < N_NODES) ? cnt[i] : 0;
  sd[t] = v;
  __syncthreads();
  #pragma unroll
  for (int off = 1; off < 256; off <<= 1) {
    const int add = (t >= off) ? sd[t - off] : 0;
    __syncthreads();
    sd[t] += add;
    __syncthreads();
  }
  if (i < N_NODES) rowL[i] = sd[t] - v;
  if (t == 255) bsum[blockIdx.x] = sd[255];
}

__global__ __launch_bounds__(256) void k_scan_bsum(
    const int* __restrict__ bsum, int* __restrict__ bpre)
{
  __shared__ int sd[256];
  const int t = threadIdx.x;
  const int v = (t < NB_SCAN) ? bsum[t] : 0;
  sd[t] = v;
  __syncthreads();
  #pragma unroll
  for (int off = 1; off < 256; off <<= 1) {
    const int add = (t >= off) ? sd[t - off] : 0;
    __syncthreads();
    sd[t] += add;
    __syncthreads();
  }
  if (t < NB_SCAN) bpre[t] = sd[t] - v;
}

// Build permutation only: einv[p] = e (4-B scattered writes, no payload).
__global__ __launch_bounds__(256) void k_perm(
    const int* __restrict__ dst, const int* __restrict__ rowL,
    const int* __restrict__ bpre, int* __restrict__ cur, int* __restrict__ einv)
{
  const int e = blockIdx.x * 256 + threadIdx.x;
  if (e >= N_EDGES) return;
  const int d = dst[e];
  const int p = rowL[d] + bpre[d >> 8] + atomicAdd(&cur[d], 1);
  einv[p] = e;
}

// Gather phase: iterate p (dst-sorted), gather edge data through LLC, write
// pexp = exp(leaky(logit)) and psrc fully coalesced. No max subtraction:
// logits ~ N(0,0.57^2) scaled by ew in [0,1] => |logit| < ~4, exp fp32-safe;
// coef = e/sum(e) is shift-invariant so this matches the reference.
__global__ __launch_bounds__(256) void k_fill2(
    const int* __restrict__ einv, const int* __restrict__ src,
    const int* __restrict__ dst, const float* __restrict__ ew,
    const float* __restrict__ al, const float* __restrict__ ar,
    float* __restrict__ pexp, int* __restrict__ psrc)
{
  const int p = blockIdx.x * 256 + threadIdx.x;
  if (p >= N_EDGES) return;
  const int e = einv[p];
  const int s = src[e], d = dst[e];
  const float w = ew[e];
  const float4 l0 = *(const float4*)&al[(long)s * 8];
  const float4 l1 = *(const float4*)&al[(long)s * 8 + 4];
  const float4 r0 = *(const float4*)&ar[(long)d * 8];
  const float4 r1 = *(const float4*)&ar[(long)d * 8 + 4];
  float lv[8] = {l0.x + r0.x, l0.y + r0.y, l0.z + r0.z, l0.w + r0.w,
                 l1.x + r1.x, l1.y + r1.y, l1.z + r1.z, l1.w + r1.w};
  #pragma unroll
  for (int h = 0; h < 8; ++h) {
    float a = w * lv[h];
    a = (a >= 0.f) ? a : 0.2f * a;   // leaky_relu(0.2)
    lv[h] = __expf(a);
  }
  psrc[p] = s;
  float4* o = (float4*)&pexp[(long)p * 8];
  o[0] = make_float4(lv[0], lv[1], lv[2], lv[3]);
  o[1] = make_float4(lv[4], lv[5], lv[6], lv[7]);
}

// One wave per node, SINGLE pass: acc += pexp * x, ssum += pexp; normalize
// at the end. No max/sum passes, no shuffles, no exp here.
__global__ __launch_bounds__(256) void k_node_agg(
    const int* __restrict__ rowL, const int* __restrict__ bpre,
    const int* __restrict__ psrc, const float* __restrict__ pexp,
    const unsigned short* __restrict__ xh, float* __restrict__ outp)
{
  const int wave = threadIdx.x >> 6;
  const int lane = threadIdx.x & 63;
  const int d = blockIdx.x * 4 + wave;
  const int start = rowL[d] + bpre[d >> 8];
  const int dn = d + 1;
  const int end = (dn == N_NODES) ? N_EDGES : (rowL[dn] + bpre[dn >> 8]);
  if (end <= start) return;   // out already holds residual; elu(0)=0

  const int h = lane >> 3;
  const int co = lane * 2;

  float2 a0 = {0.f, 0.f}, a1 = {0.f, 0.f}, a2 = {0.f, 0.f}, a3 = {0.f, 0.f};
  float s0s = 0.f, s1s = 0.f, s2s = 0.f, s3s = 0.f;
  int p = start;
  for (; p + 4 <= end; p += 4) {
    const int s0 = psrc[p + 0], s1 = psrc[p + 1];
    const int s2 = psrc[p + 2], s3 = psrc[p + 3];
    const float e0 = pexp[(long)(p + 0) * 8 + h];
    const float e1 = pexp[(long)(p + 1) * 8 + h];
    const float e2 = pexp[(long)(p + 2) * 8 + h];
    const float e3 = pexp[(long)(p + 3) * 8 + h];
    const unsigned v0 = *(const unsigned*)&xh[(long)s0 * 128 + co];
    const unsigned v1 = *(const unsigned*)&xh[(long)s1 * 128 + co];
    const unsigned v2 = *(const unsigned*)&xh[(long)s2 * 128 + co];
    const unsigned v3 = *(const unsigned*)&xh[(long)s3 * 128 + co];
    a0.x = fmaf(bflo(v0), e0, a0.x); a0.y = fmaf(bfhi(v0), e0, a0.y); s0s += e0;
    a1.x = fmaf(bflo(v1), e1, a1.x); a1.y = fmaf(bfhi(v1), e1, a1.y); s1s += e1;
    a2.x = fmaf(bflo(v2), e2, a2.x); a2.y = fmaf(bfhi(v2), e2, a2.y); s2s += e2;
    a3.x = fmaf(bflo(v3), e3, a3.x); a3.y = fmaf(bfhi(v3), e3, a3.y); s3s += e3;
  }
  for (; p < end; ++p) {
    const int s = psrc[p];
    const float e0 = pexp[(long)p * 8 + h];
    const unsigned v = *(const unsigned*)&xh[(long)s * 128 + co];
    a0.x = fmaf(bflo(v), e0, a0.x);
    a0.y = fmaf(bfhi(v), e0, a0.y);
    s0s += e0;
  }
  const float rs = 1.0f / ((s0s + s1s) + (s2s + s3s));
  const float ax = ((a0.x + a1.x) + (a2.x + a3.x)) * rs;
  const float ay = ((a0.y + a1.y) + (a2.y + a3.y)) * rs;

  float2 o = *(float2*)&outp[(long)d * 128 + co];
  o.x += (ax > 0.f) ? ax : expm1f(ax);
  o.y += (ay > 0.f) ? ay : expm1f(ay);
  *(float2*)&outp[(long)d * 128 + co] = o;
}

extern "C" void kernel_launch(void* const* d_in, const int* in_sizes, int n_in,
                              void* d_out, int out_size, void* d_ws, size_t ws_size,
                              hipStream_t stream) {
  const float* feat = (const float*)d_in[0];
  const int*   eidx = (const int*)d_in[1];
  const float* ew   = (const float*)d_in[2];
  const float* Wlin = (const float*)d_in[3];
  const float* attl = (const float*)d_in[4];
  const float* attr = (const float*)d_in[5];
  const float* Wres = (const float*)d_in[6];
  float* outp = (float*)d_out;

  float* ws = (float*)d_ws;
  unsigned short* xh = (unsigned short*)ws;
  float* al   = ws + 5120000;
  float* ar   = ws + 5440000;
  float* pexp = ws + 5760000;
  int*   psrc = (int*)(ws + 10880000);
  int*   rowL = (int*)(ws + 11520000);
  int*   cnt  = (int*)(ws + 11700000);
  int*   cur  = (int*)(ws + 11740000);   // adjacent to cnt: one memset
  int*   bsum = (int*)(ws + 11800000);
  int*   bpre = (int*)(ws + 11810000);
  unsigned short* wt = (unsigned short*)(ws + 11900000);
  int*   einv = (int*)(ws + 12000000);

  const int* src = eidx;
  const int* dst = eidx + N_EDGES;

  hipMemsetAsync(cnt, 0, (size_t)2 * N_NODES * 4, stream);  // cnt + cur

  dim3 pgrid(128, 2);
  k_prep<<<pgrid, 128, 0, stream>>>(Wlin, Wres, wt);
  dim3 ggrid(NBG, 3);  // y=0 lin, y=1 res, y=2 histogram
  k_gemm<<<ggrid, 256, 0, stream>>>(feat, wt, xh, outp, dst, cnt);
  k_alpha<<<(N_NODES * 8 + 255) / 256, 256, 0, stream>>>(xh, attl, attr, al, ar);
  k_scan_local<<<NB_SCAN, 256, 0, stream>>>(cnt, rowL, bsum);
  k_scan_bsum<<<1, 256, 0, stream>>>(bsum, bpre);
  k_perm<<<(N_EDGES + 255) / 256, 256, 0, stream>>>(dst, rowL, bpre, cur, einv);
  k_fill2<<<(N_EDGES + 255) / 256, 256, 0, stream>>>(einv, src, dst, ew, al, ar,
                                                     pexp, psrc);
  k_node_agg<<<N_NODES / 4, 256, 0, stream>>>(rowL, bpre, psrc, pexp, xh, outp);
}

// Round 11
// 198.384 us; speedup vs baseline: 1.1337x; 1.1337x over previous
//
#include <hip/hip_runtime.h>
#include <math.h>

#define N_NODES 40000
#define N_EDGES 640000
#define D 128
#define H 8
#define C 16
#define NB_SCAN 157  // ceil(40000/256)
#define NBG 1250     // 40000/32 exactly
#define KP 136       // sA k-stride (bf16 elems)

typedef __attribute__((ext_vector_type(8))) short short8;   // 8 bf16 (4 VGPRs)
typedef __attribute__((ext_vector_type(4))) float floatx4;  // MFMA C/D

// ws layout (float offsets):
//  xh    : 0          .. 2,560,000   (N*128 bf16 stored as ushort)
//  al    : 5,120,000  .. 5,440,000   (N*8)
//  ar    : 5,440,000  .. 5,760,000   (N*8)
//  pexph : 5,760,000  .. 8,320,000   (E*8 bf16 ushort, dst-sorted exp(logit))
//  psrc  : 10,880,000 .. 11,520,000  (E ints, dst-sorted src ids)
//  rowL  : 11,520,000 .. 11,560,000  (N ints, LOCAL exclusive prefix)
//  cnt   : 11,700,000 .. 11,740,000  (N ints)   | zeroed together
//  cur   : 11,740,000 .. 11,780,000  (N ints)   | (one memset)
//  bsum  : 11,800,000 .. +157
//  bpre  : 11,810,000 .. +157
//  wt    : 11,900,000 .. +8,192 floats (2x 128x128 bf16 transposed weights)

__device__ __forceinline__ unsigned short f2bf(float f) {
  const unsigned u = __float_as_uint(f);
  return (unsigned short)((u + 0x7FFFu + ((u >> 16) & 1u)) >> 16);  // RNE
}
__device__ __forceinline__ float bflo(unsigned p) {
  return __uint_as_float(p << 16);
}
__device__ __forceinline__ float bfhi(unsigned p) {
  return __uint_as_float(p & 0xFFFF0000u);
}
__device__ __forceinline__ float bf2f(unsigned short u) {
  return __uint_as_float((unsigned)u << 16);
}

// Pre-transpose W (fp32 [k][n]) -> wt (bf16 [g][n][k]). 64 KB total.
__global__ void k_prep(const float* __restrict__ Wlin,
                       const float* __restrict__ Wres,
                       unsigned short* __restrict__ wt)
{
  const int n = blockIdx.x, k = threadIdx.x, g = blockIdx.y;
  const float* W = g ? Wres : Wlin;
  wt[((g * 128 + n) * 128) + k] = f2bf(W[(long)k * 128 + n]);
}

// MFMA bf16 GEMM, 32-row blocks (grid 1250 x 3 => ~8 resident blocks/CU for
// latency pipelining). blockIdx.y: 0 = xh=bf16(feat@Wlin); 1 = outp=feat@Wres;
// 2 = dst-histogram. B frags from global wt (L2-hot, no sB). One LDS buffer:
// sA bf16 staging, reused post-MFMA as sD f32 for coalesced full-line stores.
__global__ __launch_bounds__(256, 8) void k_gemm(
    const float* __restrict__ feat, const unsigned short* __restrict__ wt,
    unsigned short* __restrict__ xh, float* __restrict__ outp,
    const int* __restrict__ dst, int* __restrict__ cnt)
{
  __shared__ float smemf[32 * 132];   // 16,896 B; sA uses first 8,704 B
  const int t = threadIdx.x;

  if (blockIdx.y == 2) {              // fused histogram
    const int stride = NBG * 256;
    for (int e = blockIdx.x * 256 + t; e < N_EDGES; e += stride)
      atomicAdd(&cnt[dst[e]], 1);
    return;
  }

  short* sA = (short*)smemf;          // [32][KP]
  float* sD = smemf;                  // [32][132]
  const int row0 = blockIdx.x * 32;
  const int g = blockIdx.y;

  // stage A: 32 rows x 128 k, fp32 -> bf16 (coalesced float4 reads)
  {
    const int kq = t & 31;            // k = kq*4
    const int rb = (t >> 5) * 4;      // 4 rows per thread
    #pragma unroll
    for (int i = 0; i < 4; ++i) {
      const int r = rb + i;
      const float4 f = *(const float4*)&feat[(long)(row0 + r) * 128 + kq * 4];
      const unsigned lo = (unsigned)f2bf(f.x) | ((unsigned)f2bf(f.y) << 16);
      const unsigned hi = (unsigned)f2bf(f.z) | ((unsigned)f2bf(f.w) << 16);
      *(uint2*)&sA[r * KP + kq * 4] = make_uint2(lo, hi);
    }
  }

  const int w = t >> 6, lane = t & 63;
  const int c15 = lane & 15, q = lane >> 4;

  // B frags: wave w owns n-tiles {2w, 2w+1}
  short8 bfr[4][2];
  const unsigned short* Wt = wt + g * 16384;
  #pragma unroll
  for (int kc = 0; kc < 4; ++kc)
    #pragma unroll
    for (int nt = 0; nt < 2; ++nt) {
      const int n = (w * 2 + nt) * 16 + c15;
      bfr[kc][nt] = *(const short8*)&Wt[n * 128 + kc * 32 + q * 8];
    }
  __syncthreads();

  floatx4 acc[2][2];
  #pragma unroll
  for (int mt = 0; mt < 2; ++mt) {
    acc[mt][0] = (floatx4){0.f, 0.f, 0.f, 0.f};
    acc[mt][1] = (floatx4){0.f, 0.f, 0.f, 0.f};
  }
  #pragma unroll
  for (int kc = 0; kc < 4; ++kc)
    #pragma unroll
    for (int mt = 0; mt < 2; ++mt) {
      const short8 afr = *(const short8*)&sA[(mt * 16 + c15) * KP + kc * 32 + q * 8];
      acc[mt][0] = __builtin_amdgcn_mfma_f32_16x16x32_bf16(afr, bfr[kc][0], acc[mt][0], 0, 0, 0);
      acc[mt][1] = __builtin_amdgcn_mfma_f32_16x16x32_bf16(afr, bfr[kc][1], acc[mt][1], 0, 0, 0);
    }
  __syncthreads();   // sA dead

  // D -> sD[32][132] (2-way banks, free)
  #pragma unroll
  for (int mt = 0; mt < 2; ++mt)
    #pragma unroll
    for (int nt = 0; nt < 2; ++nt) {
      const int col = (w * 2 + nt) * 16 + c15;
      #pragma unroll
      for (int r = 0; r < 4; ++r)
        sD[(mt * 16 + q * 4 + r) * 132 + col] = acc[mt][nt][r];
    }
  __syncthreads();

  // coalesced stores: thread -> (row = t>>3, 16-col segment = t&7)
  const int orow = t >> 3, seg = t & 7;
  const int grow = row0 + orow;
  if (g == 0) {
    #pragma unroll
    for (int i = 0; i < 2; ++i) {     // 8 cols per iter
      const float4 v0 = *(const float4*)&sD[orow * 132 + seg * 16 + i * 8];
      const float4 v1 = *(const float4*)&sD[orow * 132 + seg * 16 + i * 8 + 4];
      uint4 u;
      u.x = (unsigned)f2bf(v0.x) | ((unsigned)f2bf(v0.y) << 16);
      u.y = (unsigned)f2bf(v0.z) | ((unsigned)f2bf(v0.w) << 16);
      u.z = (unsigned)f2bf(v1.x) | ((unsigned)f2bf(v1.y) << 16);
      u.w = (unsigned)f2bf(v1.z) | ((unsigned)f2bf(v1.w) << 16);
      *(uint4*)&xh[(long)grow * 128 + seg * 16 + i * 8] = u;
    }
  } else {
    #pragma unroll
    for (int i = 0; i < 4; ++i) {
      const float4 v = *(const float4*)&sD[orow * 132 + seg * 16 + i * 4];
      *(float4*)&outp[(long)grow * 128 + seg * 16 + i * 4] = v;
    }
  }
}

// alpha_l/r from xh (bf16): thread = (node, head), 32B coalesced reads.
__global__ __launch_bounds__(256) void k_alpha(
    const unsigned short* __restrict__ xh, const float* __restrict__ attl,
    const float* __restrict__ attr, float* __restrict__ al, float* __restrict__ ar)
{
  const int gid = blockIdx.x * 256 + threadIdx.x;
  if (gid >= N_NODES * 8) return;
  const int n = gid >> 3, h = gid & 7;
  const uint4 u0 = *(const uint4*)&xh[(long)n * 128 + h * 16];
  const uint4 u1 = *(const uint4*)&xh[(long)n * 128 + h * 16 + 8];
  const unsigned vs[8] = {u0.x, u0.y, u0.z, u0.w, u1.x, u1.y, u1.z, u1.w};
  float sl = 0.f, sr = 0.f;
  #pragma unroll
  for (int j = 0; j < 8; ++j) {
    const float xlo = bflo(vs[j]), xhi = bfhi(vs[j]);
    sl = fmaf(xlo, attl[h * 16 + 2 * j], fmaf(xhi, attl[h * 16 + 2 * j + 1], sl));
    sr = fmaf(xlo, attr[h * 16 + 2 * j], fmaf(xhi, attr[h * 16 + 2 * j + 1], sr));
  }
  al[gid] = sl;
  ar[gid] = sr;
}

__global__ __launch_bounds__(256) void k_scan_local(
    const int* __restrict__ cnt, int* __restrict__ rowL, int* __restrict__ bsum)
{
  __shared__ int sd[256];
  const int t = threadIdx.x;
  const int i = blockIdx.x * 256 + t;
  const int v = (i < N_NODES) ? cnt[i] : 0;
  sd[t] = v;
  __syncthreads();
  #pragma unroll
  for (int off = 1; off < 256; off <<= 1) {
    const int add = (t >= off) ? sd[t - off] : 0;
    __syncthreads();
    sd[t] += add;
    __syncthreads();
  }
  if (i < N_NODES) rowL[i] = sd[t] - v;
  if (t == 255) bsum[blockIdx.x] = sd[255];
}

__global__ __launch_bounds__(256) void k_scan_bsum(
    const int* __restrict__ bsum, int* __restrict__ bpre)
{
  __shared__ int sd[256];
  const int t = threadIdx.x;
  const int v = (t < NB_SCAN) ? bsum[t] : 0;
  sd[t] = v;
  __syncthreads();
  #pragma unroll
  for (int off = 1; off < 256; off <<= 1) {
    const int add = (t >= off) ? sd[t - off] : 0;
    __syncthreads();
    sd[t] += add;
    __syncthreads();
  }
  if (t < NB_SCAN) bpre[t] = sd[t] - v;
}

// e-order: coalesced src/dst/ew reads, LLC-resident al/ar gathers, fused exp,
// scattered 16B pexp (bf16) + 4B psrc writes into dst-sorted slots.
// No max subtraction: logits bounded (~|4|), exp fp32-safe; coef = e/sum(e)
// is shift-invariant — validated in rounds 10 (fp32) and here (bf16 pexp).
__global__ __launch_bounds__(256) void k_fill(
    const int* __restrict__ src, const int* __restrict__ dst,
    const float* __restrict__ ew, const float* __restrict__ al,
    const float* __restrict__ ar, const int* __restrict__ rowL,
    const int* __restrict__ bpre, int* __restrict__ cur,
    unsigned short* __restrict__ pexph, int* __restrict__ psrc)
{
  const int e = blockIdx.x * 256 + threadIdx.x;
  if (e >= N_EDGES) return;
  const int s = src[e], d = dst[e];
  const float w = ew[e];
  const float4 l0 = *(const float4*)&al[(long)s * 8];
  const float4 l1 = *(const float4*)&al[(long)s * 8 + 4];
  const float4 r0 = *(const float4*)&ar[(long)d * 8];
  const float4 r1 = *(const float4*)&ar[(long)d * 8 + 4];
  float lv[8] = {l0.x + r0.x, l0.y + r0.y, l0.z + r0.z, l0.w + r0.w,
                 l1.x + r1.x, l1.y + r1.y, l1.z + r1.z, l1.w + r1.w};
  #pragma unroll
  for (int h = 0; h < 8; ++h) {
    float a = w * lv[h];
    a = (a >= 0.f) ? a : 0.2f * a;   // leaky_relu(0.2)
    lv[h] = __expf(a);
  }
  const int p = rowL[d] + bpre[d >> 8] + atomicAdd(&cur[d], 1);
  psrc[p] = s;
  uint4 u;
  u.x = (unsigned)f2bf(lv[0]) | ((unsigned)f2bf(lv[1]) << 16);
  u.y = (unsigned)f2bf(lv[2]) | ((unsigned)f2bf(lv[3]) << 16);
  u.z = (unsigned)f2bf(lv[4]) | ((unsigned)f2bf(lv[5]) << 16);
  u.w = (unsigned)f2bf(lv[6]) | ((unsigned)f2bf(lv[7]) << 16);
  *(uint4*)&pexph[(long)p * 8] = u;
}

// One wave per node, SINGLE pass: acc += pexp * x, ssum += pexp; normalize
// at the end. No max/sum passes, no shuffles, no exp here.
__global__ __launch_bounds__(256) void k_node_agg(
    const int* __restrict__ rowL, const int* __restrict__ bpre,
    const int* __restrict__ psrc, const unsigned short* __restrict__ pexph,
    const unsigned short* __restrict__ xh, float* __restrict__ outp)
{
  const int wave = threadIdx.x >> 6;
  const int lane = threadIdx.x & 63;
  const int d = blockIdx.x * 4 + wave;
  const int start = rowL[d] + bpre[d >> 8];
  const int dn = d + 1;
  const int end = (dn == N_NODES) ? N_EDGES : (rowL[dn] + bpre[dn >> 8]);
  if (end <= start) return;   // out already holds residual; elu(0)=0

  const int h = lane >> 3;
  const int co = lane * 2;

  float2 a0 = {0.f, 0.f}, a1 = {0.f, 0.f}, a2 = {0.f, 0.f}, a3 = {0.f, 0.f};
  float s0s = 0.f, s1s = 0.f, s2s = 0.f, s3s = 0.f;
  int p = start;
  for (; p + 4 <= end; p += 4) {
    const int s0 = psrc[p + 0], s1 = psrc[p + 1];
    const int s2 = psrc[p + 2], s3 = psrc[p + 3];
    const float e0 = bf2f(pexph[(long)(p + 0) * 8 + h]);
    const float e1 = bf2f(pexph[(long)(p + 1) * 8 + h]);
    const float e2 = bf2f(pexph[(long)(p + 2) * 8 + h]);
    const float e3 = bf2f(pexph[(long)(p + 3) * 8 + h]);
    const unsigned v0 = *(const unsigned*)&xh[(long)s0 * 128 + co];
    const unsigned v1 = *(const unsigned*)&xh[(long)s1 * 128 + co];
    const unsigned v2 = *(const unsigned*)&xh[(long)s2 * 128 + co];
    const unsigned v3 = *(const unsigned*)&xh[(long)s3 * 128 + co];
    a0.x = fmaf(bflo(v0), e0, a0.x); a0.y = fmaf(bfhi(v0), e0, a0.y); s0s += e0;
    a1.x = fmaf(bflo(v1), e1, a1.x); a1.y = fmaf(bfhi(v1), e1, a1.y); s1s += e1;
    a2.x = fmaf(bflo(v2), e2, a2.x); a2.y = fmaf(bfhi(v2), e2, a2.y); s2s += e2;
    a3.x = fmaf(bflo(v3), e3, a3.x); a3.y = fmaf(bfhi(v3), e3, a3.y); s3s += e3;
  }
  for (; p < end; ++p) {
    const int s = psrc[p];
    const float e0 = bf2f(pexph[(long)p * 8 + h]);
    const unsigned v = *(const unsigned*)&xh[(long)s * 128 + co];
    a0.x = fmaf(bflo(v), e0, a0.x);
    a0.y = fmaf(bfhi(v), e0, a0.y);
    s0s += e0;
  }
  const float rs = 1.0f / ((s0s + s1s) + (s2s + s3s));
  const float ax = ((a0.x + a1.x) + (a2.x + a3.x)) * rs;
  const float ay = ((a0.y + a1.y) + (a2.y + a3.y)) * rs;

  float2 o = *(float2*)&outp[(long)d * 128 + co];
  o.x += (ax > 0.f) ? ax : expm1f(ax);
  o.y += (ay > 0.f) ? ay : expm1f(ay);
  *(float2*)&outp[(long)d * 128 + co] = o;
}

extern "C" void kernel_launch(void* const* d_in, const int* in_sizes, int n_in,
                              void* d_out, int out_size, void* d_ws, size_t ws_size,
                              hipStream_t stream) {
  const float* feat = (const float*)d_in[0];
  const int*   eidx = (const int*)d_in[1];
  const float* ew   = (const float*)d_in[2];
  const float* Wlin = (const float*)d_in[3];
  const float* attl = (const float*)d_in[4];
  const float* attr = (const float*)d_in[5];
  const float* Wres = (const float*)d_in[6];
  float* outp = (float*)d_out;

  float* ws = (float*)d_ws;
  unsigned short* xh = (unsigned short*)ws;
  float* al   = ws + 5120000;
  float* ar   = ws + 5440000;
  unsigned short* pexph = (unsigned short*)(ws + 5760000);
  int*   psrc = (int*)(ws + 10880000);
  int*   rowL = (int*)(ws + 11520000);
  int*   cnt  = (int*)(ws + 11700000);
  int*   cur  = (int*)(ws + 11740000);   // adjacent to cnt: one memset
  int*   bsum = (int*)(ws + 11800000);
  int*   bpre = (int*)(ws + 11810000);
  unsigned short* wt = (unsigned short*)(ws + 11900000);

  const int* src = eidx;
  const int* dst = eidx + N_EDGES;

  hipMemsetAsync(cnt, 0, (size_t)2 * N_NODES * 4, stream);  // cnt + cur

  dim3 pgrid(128, 2);
  k_prep<<<pgrid, 128, 0, stream>>>(Wlin, Wres, wt);
  dim3 ggrid(NBG, 3);  // y=0 lin, y=1 res, y=2 histogram
  k_gemm<<<ggrid, 256, 0, stream>>>(feat, wt, xh, outp, dst, cnt);
  k_alpha<<<(N_NODES * 8 + 255) / 256, 256, 0, stream>>>(xh, attl, attr, al, ar);
  k_scan_local<<<NB_SCAN, 256, 0, stream>>>(cnt, rowL, bsum);
  k_scan_bsum<<<1, 256, 0, stream>>>(bsum, bpre);
  k_fill<<<(N_EDGES + 255) / 256, 256, 0, stream>>>(src, dst, ew, al, ar,
                                                    rowL, bpre, cur, pexph, psrc);
  k_node_agg<<<N_NODES / 4, 256, 0, stream>>>(rowL, bpre, psrc, pexph, xh, outp);
}